// Round 1
// baseline (37.669 us; speedup 1.0000x reference)
//
#include <hip/hip_runtime.h>

#define B_ 4
#define N_ 256
#define T_ 16
#define F_ 128
#define H_ 256

// ---------------------------------------------------------------------------
// Kernel 1: for a tile of 4 nodes (same b):
//   h[n][k] = mean_t nodefeat[bn][t][k]          (LDS, stored transposed [k][n])
//   a[h][n] = sum_k h[n][k] * W1[h][k]   + b1[h]
//   c[h][n] = sum_k h[n][k] * W1[h][F+k]
// Store: aT[tile][h][4]  (coalesced float4/thread, b1 folded in)
//        cT[b][h][N]     (so kernel2 reads coalesced over j)
// ---------------------------------------------------------------------------
__global__ __launch_bounds__(256) void lp_k1(const float* __restrict__ nf,
                                             const float* __restrict__ W1,
                                             const float* __restrict__ b1,
                                             float* __restrict__ aT,
                                             float* __restrict__ cT) {
    __shared__ float sh[F_ * 4];  // sh[k][n], row stride 4 floats (16B, float4-aligned)

    const int tile = blockIdx.x;      // 0..255
    const int bn0  = tile * 4;        // tiles never cross a b boundary (256 % 4 == 0)
    const int b    = bn0 >> 8;
    const int n0   = bn0 & 255;
    const int tid  = threadIdx.x;

    // ---- time-mean: 512 (n,f) pairs, 2 per thread, coalesced over f ----
#pragma unroll
    for (int r = 0; r < 2; ++r) {
        const int p = r * 256 + tid;
        const int n = p >> 7;        // 0..3
        const int f = p & 127;
        const float* src = nf + (size_t)(bn0 + n) * (T_ * F_) + f;
        float s = 0.f;
#pragma unroll
        for (int t = 0; t < T_; ++t) s += src[t * F_];
        sh[f * 4 + n] = s * (1.0f / 16.0f);
    }
    __syncthreads();

    // ---- dual GEMM: thread = output feature h ----
    const int h = tid;
    const float* w1a = W1 + (size_t)h * (2 * F_);
    const float* w1c = w1a + F_;

    float acca[4] = {0.f, 0.f, 0.f, 0.f};
    float accc[4] = {0.f, 0.f, 0.f, 0.f};

#pragma unroll 4
    for (int k = 0; k < F_; k += 4) {
        const float4 wa = *(const float4*)(w1a + k);
        const float4 wc = *(const float4*)(w1c + k);
        const float wav[4] = {wa.x, wa.y, wa.z, wa.w};
        const float wcv[4] = {wc.x, wc.y, wc.z, wc.w};
#pragma unroll
        for (int kk = 0; kk < 4; ++kk) {
            const float4 hv = *(const float4*)(sh + (k + kk) * 4);
            acca[0] = fmaf(hv.x, wav[kk], acca[0]);
            acca[1] = fmaf(hv.y, wav[kk], acca[1]);
            acca[2] = fmaf(hv.z, wav[kk], acca[2]);
            acca[3] = fmaf(hv.w, wav[kk], acca[3]);
            accc[0] = fmaf(hv.x, wcv[kk], accc[0]);
            accc[1] = fmaf(hv.y, wcv[kk], accc[1]);
            accc[2] = fmaf(hv.z, wcv[kk], accc[2]);
            accc[3] = fmaf(hv.w, wcv[kk], accc[3]);
        }
    }

    const float bb = b1[h];
    float4 av = make_float4(acca[0] + bb, acca[1] + bb, acca[2] + bb, acca[3] + bb);
    *(float4*)(aT + (size_t)tile * (H_ * 4) + h * 4) = av;

    float4 cv = make_float4(accc[0], accc[1], accc[2], accc[3]);
    *(float4*)(cT + ((size_t)b * H_ + h) * N_ + n0) = cv;
}

// ---------------------------------------------------------------------------
// Kernel 2: block = (b, i-tile of 4), thread = column j.
//   logits[b][i][j] = sum_h relu(aT[tile][h][i] + cT[b][h][j]) * W2[h] + b2
// aT tile staged in LDS (uniform ds_read_b128 broadcast per h);
// cT read coalesced over j; W2[h] is wave-uniform -> scalar loads.
// ---------------------------------------------------------------------------
__global__ __launch_bounds__(256) void lp_k2(const float* __restrict__ aT,
                                             const float* __restrict__ cT,
                                             const float* __restrict__ W2,
                                             const float* __restrict__ b2,
                                             float* __restrict__ out) {
    __shared__ float sa[H_ * 4];  // sa[h][i]

    const int tile = blockIdx.x;  // 0..255
    const int bn0  = tile * 4;
    const int b    = bn0 >> 8;
    const int i0   = bn0 & 255;
    const int tid  = threadIdx.x;  // j

    // stage a-tile: 1024 floats, coalesced, conflict-free
#pragma unroll
    for (int r = 0; r < 4; ++r) {
        const int idx = r * 256 + tid;
        sa[idx] = aT[(size_t)tile * (H_ * 4) + idx];
    }
    __syncthreads();

    const float* crow = cT + (size_t)b * (H_ * N_) + tid;

    float acc0 = 0.f, acc1 = 0.f, acc2 = 0.f, acc3 = 0.f;

#pragma unroll 4
    for (int h = 0; h < H_; ++h) {
        const float cj = crow[(size_t)h * N_];   // coalesced over threads
        const float w  = W2[h];                  // uniform -> s_load
        const float4 av = *(const float4*)(sa + h * 4);  // uniform broadcast
        float x;
        x = av.x + cj; acc0 = fmaf(fmaxf(x, 0.f), w, acc0);
        x = av.y + cj; acc1 = fmaf(fmaxf(x, 0.f), w, acc1);
        x = av.z + cj; acc2 = fmaf(fmaxf(x, 0.f), w, acc2);
        x = av.w + cj; acc3 = fmaf(fmaxf(x, 0.f), w, acc3);
    }

    const float bb = b2[0];
    const size_t base = ((size_t)b * N_ + i0) * N_ + tid;
    out[base + 0 * N_] = acc0 + bb;
    out[base + 1 * N_] = acc1 + bb;
    out[base + 2 * N_] = acc2 + bb;
    out[base + 3 * N_] = acc3 + bb;
}

extern "C" void kernel_launch(void* const* d_in, const int* in_sizes, int n_in,
                              void* d_out, int out_size, void* d_ws, size_t ws_size,
                              hipStream_t stream) {
    const float* nodefeat = (const float*)d_in[0];  // [B,N,T,F]
    const float* W1       = (const float*)d_in[1];  // [H, 2F]
    const float* b1       = (const float*)d_in[2];  // [H]
    const float* W2       = (const float*)d_in[3];  // [1, H]
    const float* b2       = (const float*)d_in[4];  // [1]
    float* out = (float*)d_out;                     // [B,N,N]

    float* aT = (float*)d_ws;                       // [256 tiles][H][4]  = 1 MB
    float* cT = aT + (size_t)256 * H_ * 4;          // [B][H][N]          = 1 MB

    lp_k1<<<256, 256, 0, stream>>>(nodefeat, W1, b1, aT, cT);
    lp_k2<<<256, 256, 0, stream>>>(aT, cT, W2, b2, out);
}

// Round 2
// 25.430 us; speedup vs baseline: 1.4813x; 1.4813x over previous
//
#include <hip/hip_runtime.h>

#define B_ 4
#define N_ 256
#define T_ 16
#define F_ 128
#define H_ 256

// ---------------------------------------------------------------------------
// Kernel 1: tile of 4 nodes (same b), block = 1024 threads (4 waves/SIMD).
//   phase 1 (all 1024 threads): h[n][f] = mean_t nodefeat[bn][t][f]
//            threads split the 16 t's into 2 halves, LDS combine.
//   phase 2: threads = (kq in 0..3, h in 0..255); each accumulates the
//            partial dual-GEMM over its 32-wide k chunk (8 accumulators).
//   phase 3: threads 0..255 (=h) sum the 4 k-partials, fold b1, store:
//              aT[tile][h][4]  (b1 folded)
//              cT[b][h][N]     (so kernel2 reads coalesced over j)
// ---------------------------------------------------------------------------
__global__ __launch_bounds__(1024) void lp_k1(const float* __restrict__ nf,
                                              const float* __restrict__ W1,
                                              const float* __restrict__ b1,
                                              float* __restrict__ aT,
                                              float* __restrict__ cT) {
    __shared__ float sh[F_ * 4];      // mean, transposed [k][n] (2 KB)
    __shared__ float red[8 * 1024];   // reduction scratch (32 KB)

    const int tile = blockIdx.x;      // 0..255
    const int bn0  = tile * 4;
    const int b    = bn0 >> 8;
    const int n0   = bn0 & 255;
    const int tid  = threadIdx.x;

    // ---- phase 1: time-mean partials (coalesced over f within each group) --
    {
        const int gh = tid >> 9;      // t-half: 0 or 1
        const int p  = tid & 511;
        const int n  = p >> 7;        // 0..3
        const int f  = p & 127;
        const float* src = nf + (size_t)(bn0 + n) * (T_ * F_) + gh * 8 * F_ + f;
        float s = 0.f;
#pragma unroll
        for (int t = 0; t < 8; ++t) s += src[t * F_];
        red[tid] = s;
    }
    __syncthreads();
    if (tid < 512) {
        const int n = tid >> 7;
        const int f = tid & 127;
        sh[f * 4 + n] = (red[tid] + red[512 + tid]) * (1.0f / 16.0f);
    }
    __syncthreads();

    // ---- phase 2: dual GEMM, k split 4 ways ----
    const int kq = tid >> 8;          // 0..3
    const int h  = tid & 255;
    const float* w1a = W1 + (size_t)h * (2 * F_) + kq * 32;
    const float* w1c = w1a + F_;
    const float* shk = sh + kq * 32 * 4;

    float acca[4] = {0.f, 0.f, 0.f, 0.f};
    float accc[4] = {0.f, 0.f, 0.f, 0.f};

#pragma unroll
    for (int kk = 0; kk < 32; kk += 4) {
        const float4 wa = *(const float4*)(w1a + kk);
        const float4 wc = *(const float4*)(w1c + kk);
        const float wav[4] = {wa.x, wa.y, wa.z, wa.w};
        const float wcv[4] = {wc.x, wc.y, wc.z, wc.w};
#pragma unroll
        for (int e = 0; e < 4; ++e) {
            const float4 hv = *(const float4*)(shk + (kk + e) * 4);
            acca[0] = fmaf(hv.x, wav[e], acca[0]);
            acca[1] = fmaf(hv.y, wav[e], acca[1]);
            acca[2] = fmaf(hv.z, wav[e], acca[2]);
            acca[3] = fmaf(hv.w, wav[e], acca[3]);
            accc[0] = fmaf(hv.x, wcv[e], accc[0]);
            accc[1] = fmaf(hv.y, wcv[e], accc[1]);
            accc[2] = fmaf(hv.z, wcv[e], accc[2]);
            accc[3] = fmaf(hv.w, wcv[e], accc[3]);
        }
    }

    // ---- phase 3: LDS reduce over kq (scalar writes/reads, conflict-free) --
#pragma unroll
    for (int e = 0; e < 4; ++e) {
        red[(e)     * 1024 + kq * 256 + h] = acca[e];
        red[(4 + e) * 1024 + kq * 256 + h] = accc[e];
    }
    __syncthreads();

    if (tid < 256) {
        float ra[4], rc[4];
#pragma unroll
        for (int e = 0; e < 4; ++e) {
            const float* pa = red + e * 1024 + tid;
            const float* pc = red + (4 + e) * 1024 + tid;
            ra[e] = (pa[0] + pa[256]) + (pa[512] + pa[768]);
            rc[e] = (pc[0] + pc[256]) + (pc[512] + pc[768]);
        }
        const float bb = b1[tid];
        *(float4*)(aT + (size_t)tile * (H_ * 4) + tid * 4) =
            make_float4(ra[0] + bb, ra[1] + bb, ra[2] + bb, ra[3] + bb);
        *(float4*)(cT + ((size_t)b * H_ + tid) * N_ + n0) =
            make_float4(rc[0], rc[1], rc[2], rc[3]);
    }
}

// ---------------------------------------------------------------------------
// Kernel 2: block = (b, i-tile of 4), 1024 threads = (hq in 0..3, j in 0..255).
//   logits[b][i][j] = sum_h relu(aT[tile][h][i] + cT[b][h][j]) * W2[h] + b2
// Each thread accumulates 4 rows over its 64-wide h chunk:
//   cT load coalesced over j; a-tile uniform LDS broadcast; W2 uniform s_load.
// Partials reduced via LDS [row][hq][j] (conflict-free), all threads store.
// ---------------------------------------------------------------------------
__global__ __launch_bounds__(1024) void lp_k2(const float* __restrict__ aT,
                                              const float* __restrict__ cT,
                                              const float* __restrict__ W2,
                                              const float* __restrict__ b2,
                                              float* __restrict__ out) {
    __shared__ float sa[H_ * 4];        // a-tile (4 KB)
    __shared__ float pr[4][4][256];     // [row][hq][j] partials (16 KB)

    const int tile = blockIdx.x;        // 0..255
    const int bn0  = tile * 4;
    const int b    = bn0 >> 8;
    const int i0   = bn0 & 255;
    const int tid  = threadIdx.x;
    const int hq   = tid >> 8;          // 0..3
    const int j    = tid & 255;

    sa[tid] = aT[(size_t)tile * (H_ * 4) + tid];
    __syncthreads();

    const float* crow = cT + (size_t)b * (H_ * N_) + j;
    const int h0 = hq * 64;

    float acc0 = 0.f, acc1 = 0.f, acc2 = 0.f, acc3 = 0.f;

#pragma unroll 4
    for (int hh = 0; hh < 64; ++hh) {
        const int h = h0 + hh;
        const float cj = crow[(size_t)h * N_];           // coalesced over j
        const float w  = W2[h];                          // uniform -> s_load
        const float4 av = *(const float4*)(sa + h * 4);  // uniform broadcast
        float x;
        x = av.x + cj; acc0 = fmaf(fmaxf(x, 0.f), w, acc0);
        x = av.y + cj; acc1 = fmaf(fmaxf(x, 0.f), w, acc1);
        x = av.z + cj; acc2 = fmaf(fmaxf(x, 0.f), w, acc2);
        x = av.w + cj; acc3 = fmaf(fmaxf(x, 0.f), w, acc3);
    }

    pr[0][hq][j] = acc0;
    pr[1][hq][j] = acc1;
    pr[2][hq][j] = acc2;
    pr[3][hq][j] = acc3;
    __syncthreads();

    // reduce: 1024 threads = (row, j); 4 scalar LDS reads each, conflict-free
    {
        const int r  = tid >> 8;        // 0..3
        const int jj = tid & 255;
        const float s = (pr[r][0][jj] + pr[r][1][jj]) + (pr[r][2][jj] + pr[r][3][jj]);
        out[((size_t)b * N_ + (i0 + r)) * N_ + jj] = s + b2[0];
    }
}

extern "C" void kernel_launch(void* const* d_in, const int* in_sizes, int n_in,
                              void* d_out, int out_size, void* d_ws, size_t ws_size,
                              hipStream_t stream) {
    const float* nodefeat = (const float*)d_in[0];  // [B,N,T,F]
    const float* W1       = (const float*)d_in[1];  // [H, 2F]
    const float* b1       = (const float*)d_in[2];  // [H]
    const float* W2       = (const float*)d_in[3];  // [1, H]
    const float* b2       = (const float*)d_in[4];  // [1]
    float* out = (float*)d_out;                     // [B,N,N]

    float* aT = (float*)d_ws;                       // [256 tiles][H][4]  = 1 MB
    float* cT = aT + (size_t)256 * H_ * 4;          // [B][H][N]          = 1 MB

    lp_k1<<<256, 1024, 0, stream>>>(nodefeat, W1, b1, aT, cT);
    lp_k2<<<256, 1024, 0, stream>>>(aT, cT, W2, b2, out);
}